// Round 3
// baseline (423.365 us; speedup 1.0000x reference)
//
#include <hip/hip_runtime.h>
#include <math.h>

namespace {
constexpr int NB = 256;   // batch
constexpr int NR = 1152;  // routes
constexpr int NC = 10;    // output capsules
constexpr int NO = 16;    // output dim
constexpr int NI = 8;     // input dim
}

// b = 0, c = 1/R  (softmax of zeros over R)
__global__ __launch_bounds__(256) void k_init(float* __restrict__ bbuf,
                                              float* __restrict__ cbuf) {
    int i = blockIdx.x * 256 + threadIdx.x;
    if (i < NR * NC) { bbuf[i] = 0.0f; cbuf[i] = 1.0f / NR; }
}

// xT[r][b][i] = x[b][r][i], LDS-staged: tile = 8 b x 128 r
__global__ __launch_bounds__(256) void k_transpose(const float* __restrict__ x,
                                                   float* __restrict__ xT) {
    __shared__ float t[8][1028];   // 1024 + 4 pad (bank spread)
    const int rb = blockIdx.x;     // 9 tiles of 128 r
    const int bb = blockIdx.y;     // 32 tiles of 8 b
    #pragma unroll
    for (int k = 0; k < 8; ++k) {
        const float4* src = reinterpret_cast<const float4*>(
            x + ((size_t)(bb * 8 + k) * NR + rb * 128) * NI);
        *reinterpret_cast<float4*>(&t[k][threadIdx.x * 4]) = src[threadIdx.x];
    }
    __syncthreads();
    #pragma unroll
    for (int it = 0; it < 8; ++it) {
        int f  = it * 256 + threadIdx.x;   // 0..2047 float4s
        int i4 = f & 1;
        int b  = (f >> 1) & 7;
        int r  = f >> 4;
        float4 v = *reinterpret_cast<float4*>(&t[b][r * 8 + i4 * 4]);
        *reinterpret_cast<float4*>(
            xT + ((size_t)(rb * 128 + r) * NB + bb * 8 + b) * NI + i4 * 4) = v;
    }
}

// part[c][ch][b][o] = sum_{r in chunk} c[r,c] * sum_i W[r,c,o,i] * x[b,r,i]
// wave = og (4 o's), lane = 4 consecutive b's. W wave-uniform (scalar path).
// 1-deep software pipeline on x. launch_bounds(...,2) -> VGPR cap 256.
__global__ __launch_bounds__(256, 2) void k_partial(const float* __restrict__ xT,
                                                    const float* __restrict__ W,
                                                    const float* __restrict__ cbuf,
                                                    float* __restrict__ part,
                                                    int nchunk, int rch) {
    const int ch = blockIdx.x;
    const int c  = blockIdx.y;
    const int r0 = ch * rch;
    const int bg = threadIdx.x & 63;
    const int og = __builtin_amdgcn_readfirstlane(threadIdx.x >> 6);

    float acc[4][4];
    #pragma unroll
    for (int k = 0; k < 4; ++k)
        #pragma unroll
        for (int oo = 0; oo < 4; ++oo) acc[k][oo] = 0.0f;

    const float* xbase = xT + ((size_t)r0 * NB + (size_t)bg * 4) * NI;
    const float* wbase = W + (((size_t)r0 * NC + c) * NO + (size_t)og * 4) * NI;

    float4 xv[8];
    {
        const float4* xp = reinterpret_cast<const float4*>(xbase);
        #pragma unroll
        for (int j = 0; j < 8; ++j) xv[j] = xp[j];
    }

    for (int rr = 0; rr < rch; ++rr) {
        float4 xn[8];
        const bool more = (rr + 1 < rch);
        if (more) {
            const float4* xp = reinterpret_cast<const float4*>(
                xbase + (size_t)(rr + 1) * NB * NI);
            #pragma unroll
            for (int j = 0; j < 8; ++j) xn[j] = xp[j];
        }
        const float* wp = wbase + (size_t)rr * (NC * NO * NI);
        float w[32];
        #pragma unroll
        for (int j = 0; j < 32; ++j) w[j] = wp[j];
        const float cr = cbuf[(size_t)(r0 + rr) * NC + c];

        #pragma unroll
        for (int k = 0; k < 4; ++k) {
            float4 xa = xv[2 * k], xb = xv[2 * k + 1];
            #pragma unroll
            for (int oo = 0; oo < 4; ++oo) {
                const float* wo = &w[oo * 8];
                float dot = wo[0] * xa.x + wo[1] * xa.y + wo[2] * xa.z + wo[3] * xa.w
                          + wo[4] * xb.x + wo[5] * xb.y + wo[6] * xb.z + wo[7] * xb.w;
                acc[k][oo] = fmaf(cr, dot, acc[k][oo]);
            }
        }
        if (more) {
            #pragma unroll
            for (int j = 0; j < 8; ++j) xv[j] = xn[j];
        }
    }

    float* pp = part + (((size_t)c * nchunk + ch) * NB + (size_t)bg * 4) * NO + og * 4;
    #pragma unroll
    for (int k = 0; k < 4; ++k)
        *reinterpret_cast<float4*>(pp + (size_t)k * NO) =
            make_float4(acc[k][0], acc[k][1], acc[k][2], acc[k][3]);
}

// s[c,b,o] = sum_ch part ; v = squash(s); vbuf[c][b][o] or out[b][c][o]
__global__ __launch_bounds__(256) void k_reduce(const float* __restrict__ part,
                                                float* __restrict__ vbuf,
                                                float* __restrict__ out,
                                                int nchunk, int final_pass) {
    int gid = blockIdx.x * 256 + threadIdx.x;
    int o  = gid & 15;
    int cb = gid >> 4;
    int b  = cb & 255;
    int c  = cb >> 8;
    float s = 0.0f;
    const float* p = part + ((size_t)c * nchunk * NB + b) * NO + o;
    for (int ch = 0; ch < nchunk; ++ch) s += p[(size_t)ch * NB * NO];
    float v = s * fabsf(s) / (1.0f + s * s);
    if (final_pass) {
        out[((size_t)b * NC + c) * NO + o] = v;
    } else {
        vbuf[gid] = v;
    }
}

// bbuf[r,c] += (1/B) * sum_b sum_o (sum_i W[r,c,o,i] x[b,r,i]) * v[c,b,o]
// partials held in registers (full unroll), shuffles deferred past the loop.
template <int RCH>
__global__ __launch_bounds__(256, 2) void k_agree(const float* __restrict__ xT,
                                                  const float* __restrict__ W,
                                                  const float* __restrict__ vbuf,
                                                  float* __restrict__ bbuf) {
    const int ch = blockIdx.x;
    const int c  = blockIdx.y;
    const int r0 = ch * RCH;
    const int bg = threadIdx.x & 63;
    const int og = __builtin_amdgcn_readfirstlane(threadIdx.x >> 6);

    __shared__ float red[4][RCH];

    float4 vv[4];
    #pragma unroll
    for (int k = 0; k < 4; ++k)
        vv[k] = *reinterpret_cast<const float4*>(
            vbuf + ((size_t)c * NB + (size_t)bg * 4 + k) * NO + og * 4);

    const float* xbase = xT + ((size_t)r0 * NB + (size_t)bg * 4) * NI;
    const float* wbase = W + (((size_t)r0 * NC + c) * NO + (size_t)og * 4) * NI;

    float partl[RCH];
    float4 xv[8];
    {
        const float4* xp = reinterpret_cast<const float4*>(xbase);
        #pragma unroll
        for (int j = 0; j < 8; ++j) xv[j] = xp[j];
    }

    #pragma unroll
    for (int rr = 0; rr < RCH; ++rr) {
        float4 xn[8];
        if (rr + 1 < RCH) {   // compile-time per unrolled body
            const float4* xp = reinterpret_cast<const float4*>(
                xbase + (size_t)(rr + 1) * NB * NI);
            #pragma unroll
            for (int j = 0; j < 8; ++j) xn[j] = xp[j];
        }
        const float* wp = wbase + (size_t)rr * (NC * NO * NI);
        float w[32];
        #pragma unroll
        for (int j = 0; j < 32; ++j) w[j] = wp[j];

        float p = 0.0f;
        #pragma unroll
        for (int k = 0; k < 4; ++k) {
            float4 xa = xv[2 * k], xb = xv[2 * k + 1];
            float4 vk = vv[k];
            #pragma unroll
            for (int oo = 0; oo < 4; ++oo) {
                const float* wo = &w[oo * 8];
                float dot = wo[0] * xa.x + wo[1] * xa.y + wo[2] * xa.z + wo[3] * xa.w
                          + wo[4] * xb.x + wo[5] * xb.y + wo[6] * xb.z + wo[7] * xb.w;
                p = fmaf(dot, (oo == 0) ? vk.x : (oo == 1) ? vk.y : (oo == 2) ? vk.z : vk.w, p);
            }
        }
        partl[rr] = p;
        if (rr + 1 < RCH) {
            #pragma unroll
            for (int j = 0; j < 8; ++j) xv[j] = xn[j];
        }
    }

    #pragma unroll
    for (int rr = 0; rr < RCH; ++rr) {
        float p = partl[rr];
        p += __shfl_xor(p, 1);
        p += __shfl_xor(p, 2);
        p += __shfl_xor(p, 4);
        p += __shfl_xor(p, 8);
        p += __shfl_xor(p, 16);
        p += __shfl_xor(p, 32);
        if (bg == 0) red[og][rr] = p;
    }
    __syncthreads();
    if (threadIdx.x < RCH) {
        int rr = threadIdx.x;
        float a = red[0][rr] + red[1][rr] + red[2][rr] + red[3][rr];
        bbuf[(r0 + rr) * NC + c] += a * (1.0f / NB);
    }
}

// softmax over r (axis 0) per column c
__global__ __launch_bounds__(256) void k_softmax(const float* __restrict__ bbuf,
                                                 float* __restrict__ cbuf) {
    const int c   = blockIdx.x;
    const int tid = threadIdx.x;
    __shared__ float sred[4];
    __shared__ float sred2[4];
    int wave = tid >> 6, lane = tid & 63;

    float m = -1e30f;
    for (int r = tid; r < NR; r += 256) m = fmaxf(m, bbuf[r * NC + c]);
    #pragma unroll
    for (int off = 1; off < 64; off <<= 1) m = fmaxf(m, __shfl_xor(m, off));
    if (lane == 0) sred[wave] = m;
    __syncthreads();
    m = fmaxf(fmaxf(sred[0], sred[1]), fmaxf(sred[2], sred[3]));

    float s = 0.0f;
    for (int r = tid; r < NR; r += 256) {
        float e = expf(bbuf[r * NC + c] - m);
        cbuf[r * NC + c] = e;
        s += e;
    }
    #pragma unroll
    for (int off = 1; off < 64; off <<= 1) s += __shfl_xor(s, off);
    if (lane == 0) sred2[wave] = s;
    __syncthreads();
    s = sred2[0] + sred2[1] + sred2[2] + sred2[3];
    float inv = 1.0f / s;
    for (int r = tid; r < NR; r += 256) cbuf[r * NC + c] *= inv;
}

extern "C" void kernel_launch(void* const* d_in, const int* in_sizes, int n_in,
                              void* d_out, int out_size, void* d_ws, size_t ws_size,
                              hipStream_t stream) {
    const float* x = (const float*)d_in[0];   // [256,1152,8]
    const float* W = (const float*)d_in[1];   // [1152,10,16,8]
    float* out = (float*)d_out;               // [256,10,16,1]

    auto need_bytes = [](int nch) -> size_t {
        return sizeof(float) * ((size_t)NC * nch * NB * NO +   // part
                                (size_t)NR * NB * NI +         // xT
                                2 * (size_t)NR * NC +          // bbuf, cbuf
                                (size_t)NC * NB * NO);         // vbuf
    };
    int nchunk = (ws_size >= need_bytes(128)) ? 128
               : (ws_size >= need_bytes(64))  ? 64 : 32;
    int rch = NR / nchunk;   // 9, 18 or 36

    float* part = (float*)d_ws;
    float* xT   = part + (size_t)NC * nchunk * NB * NO;
    float* bbuf = xT + (size_t)NR * NB * NI;
    float* cbuf = bbuf + (size_t)NR * NC;
    float* vbuf = cbuf + (size_t)NR * NC;

    k_init<<<(NR * NC + 255) / 256, 256, 0, stream>>>(bbuf, cbuf);
    {
        dim3 gt(NR / 128, NB / 8);   // (9, 32)
        k_transpose<<<gt, 256, 0, stream>>>(x, xT);
    }

    // grid = (ch, c): blocks sharing an x-slice are spaced nchunk (mult of 8)
    // apart in linear id -> same XCD -> L2-local x reuse.
    dim3 gpart(nchunk, NC);
    int  gred = (NC * NB * NO) / 256;   // 160 blocks

    for (int it = 0; it < 3; ++it) {
        k_partial<<<gpart, 256, 0, stream>>>(xT, W, cbuf, part, nchunk, rch);
        k_reduce<<<gred, 256, 0, stream>>>(part, vbuf, out, nchunk, it == 2 ? 1 : 0);
        if (it < 2) {
            if (rch == 9)
                k_agree<9><<<gpart, 256, 0, stream>>>(xT, W, vbuf, bbuf);
            else if (rch == 18)
                k_agree<18><<<gpart, 256, 0, stream>>>(xT, W, vbuf, bbuf);
            else
                k_agree<36><<<gpart, 256, 0, stream>>>(xT, W, vbuf, bbuf);
            k_softmax<<<NC, 256, 0, stream>>>(bbuf, cbuf);
        }
    }
}

// Round 4
// 289.469 us; speedup vs baseline: 1.4626x; 1.4626x over previous
//
#include <hip/hip_runtime.h>
#include <math.h>

namespace {
constexpr int NB = 256;   // batch
constexpr int NR = 1152;  // routes
constexpr int NC = 10;    // output capsules
constexpr int NO = 16;    // output dim
constexpr int NI = 8;     // input dim
}

// b = 0, c = 1/R  (softmax of zeros over R)
__global__ __launch_bounds__(256) void k_init(float* __restrict__ bbuf,
                                              float* __restrict__ cbuf) {
    int i = blockIdx.x * 256 + threadIdx.x;
    if (i < NR * NC) { bbuf[i] = 0.0f; cbuf[i] = 1.0f / NR; }
}

// xT[r][b][i] = x[b][r][i], LDS-staged: tile = 8 b x 128 r
__global__ __launch_bounds__(256) void k_transpose(const float* __restrict__ x,
                                                   float* __restrict__ xT) {
    __shared__ float t[8][1028];
    const int rb = blockIdx.x;     // 9 tiles of 128 r
    const int bb = blockIdx.y;     // 32 tiles of 8 b
    #pragma unroll
    for (int k = 0; k < 8; ++k) {
        const float4* src = reinterpret_cast<const float4*>(
            x + ((size_t)(bb * 8 + k) * NR + rb * 128) * NI);
        *reinterpret_cast<float4*>(&t[k][threadIdx.x * 4]) = src[threadIdx.x];
    }
    __syncthreads();
    #pragma unroll
    for (int it = 0; it < 8; ++it) {
        int f  = it * 256 + threadIdx.x;
        int i4 = f & 1;
        int b  = (f >> 1) & 7;
        int r  = f >> 4;
        float4 v = *reinterpret_cast<float4*>(&t[b][r * 8 + i4 * 4]);
        *reinterpret_cast<float4*>(
            xT + ((size_t)(rb * 128 + r) * NB + bb * 8 + b) * NI + i4 * 4) = v;
    }
}

// part float4 layout: P(c,ch,og,b) = ((c*NCH+ch)*4+og)*NB + b   (component = oo)
// wave = og (4 o's), lane = 4 consecutive b's. W wave-uniform -> s_load path.
// NO manual pipeline arrays; compile-time RCH; VGPR target 128 (4 waves/SIMD).
template <int NCH, int RCH>
__global__ __launch_bounds__(256, 4) void k_partial(const float* __restrict__ xT,
                                                    const float* __restrict__ W,
                                                    const float* __restrict__ cbuf,
                                                    float4* __restrict__ part) {
    const int ch = blockIdx.x;
    const int c  = blockIdx.y;
    const int r0 = ch * RCH;
    const int bg = threadIdx.x & 63;
    const int og = __builtin_amdgcn_readfirstlane(threadIdx.x >> 6);

    float acc[4][4] = {};

    const float* xbase = xT + ((size_t)r0 * NB + (size_t)bg * 4) * NI;
    const float* wbase = W + (((size_t)r0 * NC + c) * NO + (size_t)og * 4) * NI;

    #pragma unroll
    for (int rr = 0; rr < RCH; ++rr) {
        const float4* xp = reinterpret_cast<const float4*>(
            xbase + (size_t)rr * NB * NI);
        float4 xv[8];
        #pragma unroll
        for (int j = 0; j < 8; ++j) xv[j] = xp[j];

        const float* wp = wbase + (size_t)rr * (NC * NO * NI);
        float w[32];
        #pragma unroll
        for (int j = 0; j < 32; ++j) w[j] = wp[j];
        const float cr = cbuf[(size_t)(r0 + rr) * NC + c];

        #pragma unroll
        for (int k = 0; k < 4; ++k) {
            float4 xa = xv[2 * k], xb = xv[2 * k + 1];
            #pragma unroll
            for (int oo = 0; oo < 4; ++oo) {
                const float* wo = &w[oo * 8];
                float dot = wo[0] * xa.x + wo[1] * xa.y + wo[2] * xa.z + wo[3] * xa.w
                          + wo[4] * xb.x + wo[5] * xb.y + wo[6] * xb.z + wo[7] * xb.w;
                acc[k][oo] = fmaf(cr, dot, acc[k][oo]);
            }
        }
    }

    // 64B contiguous per lane, 16KB contiguous per wave
    float4* pp = part + ((size_t)(c * NCH + ch) * 4 + og) * NB + bg * 4;
    #pragma unroll
    for (int k = 0; k < 4; ++k)
        pp[k] = make_float4(acc[k][0], acc[k][1], acc[k][2], acc[k][3]);
}

// stage1: sum 8 chunks -> part2[f][e], f=(c*4+og)*NB+b, e in [0,E)
__global__ __launch_bounds__(256) void k_reduce1(const float4* __restrict__ part,
                                                 float4* __restrict__ part2,
                                                 int NCH_rt, int E) {
    int f = blockIdx.x * 256 + threadIdx.x;   // [0, 10240)
    int e = blockIdx.y;
    int b  = f & 255;
    int cg = f >> 8;          // c*4+og
    int og = cg & 3;
    int c  = cg >> 2;
    const float4* p = part + ((size_t)c * NCH_rt * 4 + og) * NB + b;
    float4 s = make_float4(0.f, 0.f, 0.f, 0.f);
    int ch0 = e * 8;
    #pragma unroll
    for (int k = 0; k < 8; ++k) {
        float4 v = p[(size_t)(ch0 + k) * 4 * NB];
        s.x += v.x; s.y += v.y; s.z += v.z; s.w += v.w;
    }
    part2[(size_t)f * E + e] = s;
}

// stage2: sum E partials, squash, write vbuf[c][b][o] or out[b][c][o]
__global__ __launch_bounds__(256) void k_reduce2(const float4* __restrict__ part2,
                                                 float* __restrict__ vbuf,
                                                 float* __restrict__ out,
                                                 int E, int final_pass) {
    int f = blockIdx.x * 256 + threadIdx.x;   // [0, 10240)
    int b  = f & 255;
    int cg = f >> 8;
    int og = cg & 3;
    int c  = cg >> 2;
    const float4* p = part2 + (size_t)f * E;
    float4 s = make_float4(0.f, 0.f, 0.f, 0.f);
    for (int e = 0; e < E; ++e) {
        float4 v = p[e];
        s.x += v.x; s.y += v.y; s.z += v.z; s.w += v.w;
    }
    float vr[4];
    vr[0] = s.x * fabsf(s.x) / (1.0f + s.x * s.x);
    vr[1] = s.y * fabsf(s.y) / (1.0f + s.y * s.y);
    vr[2] = s.z * fabsf(s.z) / (1.0f + s.z * s.z);
    vr[3] = s.w * fabsf(s.w) / (1.0f + s.w * s.w);
    if (final_pass) {
        float* op = out + ((size_t)b * NC + c) * NO + og * 4;
        #pragma unroll
        for (int oo = 0; oo < 4; ++oo) op[oo] = vr[oo];
    } else {
        float* vp = vbuf + ((size_t)c * NB + b) * NO + og * 4;
        #pragma unroll
        for (int oo = 0; oo < 4; ++oo) vp[oo] = vr[oo];
    }
}

// bbuf[r,c] += (1/B) * sum_b sum_o (sum_i W[r,c,o,i] x[b,r,i]) * v[c,b,o]
// per-rr: one LDS store per lane; single post-loop block reduction.
template <int NCH, int RCH>
__global__ __launch_bounds__(256, 4) void k_agree(const float* __restrict__ xT,
                                                  const float* __restrict__ W,
                                                  const float* __restrict__ vbuf,
                                                  float* __restrict__ bbuf) {
    const int ch = blockIdx.x;
    const int c  = blockIdx.y;
    const int r0 = ch * RCH;
    const int bg = threadIdx.x & 63;
    const int og = __builtin_amdgcn_readfirstlane(threadIdx.x >> 6);

    __shared__ float plds[RCH][256];

    float4 vv[4];
    #pragma unroll
    for (int k = 0; k < 4; ++k)
        vv[k] = *reinterpret_cast<const float4*>(
            vbuf + ((size_t)c * NB + (size_t)bg * 4 + k) * NO + og * 4);

    const float* xbase = xT + ((size_t)r0 * NB + (size_t)bg * 4) * NI;
    const float* wbase = W + (((size_t)r0 * NC + c) * NO + (size_t)og * 4) * NI;

    #pragma unroll
    for (int rr = 0; rr < RCH; ++rr) {
        const float4* xp = reinterpret_cast<const float4*>(
            xbase + (size_t)rr * NB * NI);
        float4 xv[8];
        #pragma unroll
        for (int j = 0; j < 8; ++j) xv[j] = xp[j];

        const float* wp = wbase + (size_t)rr * (NC * NO * NI);
        float w[32];
        #pragma unroll
        for (int j = 0; j < 32; ++j) w[j] = wp[j];

        float p = 0.0f;
        #pragma unroll
        for (int k = 0; k < 4; ++k) {
            float4 xa = xv[2 * k], xb = xv[2 * k + 1];
            float4 vk = vv[k];
            #pragma unroll
            for (int oo = 0; oo < 4; ++oo) {
                const float* wo = &w[oo * 8];
                float dot = wo[0] * xa.x + wo[1] * xa.y + wo[2] * xa.z + wo[3] * xa.w
                          + wo[4] * xb.x + wo[5] * xb.y + wo[6] * xb.z + wo[7] * xb.w;
                p = fmaf(dot, (oo == 0) ? vk.x : (oo == 1) ? vk.y
                              : (oo == 2) ? vk.z : vk.w, p);
            }
        }
        plds[rr][threadIdx.x] = p;
    }
    __syncthreads();

    // wave og reduces rr = og, og+4, ...
    for (int rr = og; rr < RCH; rr += 4) {
        float s = plds[rr][bg] + plds[rr][bg + 64]
                + plds[rr][bg + 128] + plds[rr][bg + 192];
        s += __shfl_xor(s, 1);
        s += __shfl_xor(s, 2);
        s += __shfl_xor(s, 4);
        s += __shfl_xor(s, 8);
        s += __shfl_xor(s, 16);
        s += __shfl_xor(s, 32);
        if (bg == 0) bbuf[(size_t)(r0 + rr) * NC + c] += s * (1.0f / NB);
    }
}

// softmax over r (axis 0) per column c
__global__ __launch_bounds__(256) void k_softmax(const float* __restrict__ bbuf,
                                                 float* __restrict__ cbuf) {
    const int c   = blockIdx.x;
    const int tid = threadIdx.x;
    __shared__ float sred[4];
    __shared__ float sred2[4];
    int wave = tid >> 6, lane = tid & 63;

    float m = -1e30f;
    for (int r = tid; r < NR; r += 256) m = fmaxf(m, bbuf[r * NC + c]);
    #pragma unroll
    for (int off = 1; off < 64; off <<= 1) m = fmaxf(m, __shfl_xor(m, off));
    if (lane == 0) sred[wave] = m;
    __syncthreads();
    m = fmaxf(fmaxf(sred[0], sred[1]), fmaxf(sred[2], sred[3]));

    float s = 0.0f;
    for (int r = tid; r < NR; r += 256) {
        float e = expf(bbuf[r * NC + c] - m);
        cbuf[r * NC + c] = e;
        s += e;
    }
    #pragma unroll
    for (int off = 1; off < 64; off <<= 1) s += __shfl_xor(s, off);
    if (lane == 0) sred2[wave] = s;
    __syncthreads();
    s = sred2[0] + sred2[1] + sred2[2] + sred2[3];
    float inv = 1.0f / s;
    for (int r = tid; r < NR; r += 256) cbuf[r * NC + c] *= inv;
}

extern "C" void kernel_launch(void* const* d_in, const int* in_sizes, int n_in,
                              void* d_out, int out_size, void* d_ws, size_t ws_size,
                              hipStream_t stream) {
    const float* x = (const float*)d_in[0];   // [256,1152,8]
    const float* W = (const float*)d_in[1];   // [1152,10,16,8]
    float* out = (float*)d_out;               // [256,10,16,1]

    auto need_bytes = [](int nch) -> size_t {
        return sizeof(float) * ((size_t)NC * nch * NB * NO +     // part
                                (size_t)10240 * (nch / 8) * 4 +  // part2
                                (size_t)NR * NB * NI +           // xT
                                2 * (size_t)NR * NC +            // bbuf, cbuf
                                (size_t)NC * NB * NO);           // vbuf
    };
    int nchunk = (ws_size >= need_bytes(128)) ? 128
               : (ws_size >= need_bytes(64))  ? 64 : 32;
    int E = nchunk / 8;

    float4* part  = (float4*)d_ws;                                  // NC*nchunk*4*NB float4
    float4* part2 = part + (size_t)NC * nchunk * 4 * NB;            // 10240*E float4
    float*  xT    = (float*)(part2 + (size_t)10240 * E);            // NR*NB*NI
    float*  bbuf  = xT + (size_t)NR * NB * NI;
    float*  cbuf  = bbuf + (size_t)NR * NC;
    float*  vbuf  = cbuf + (size_t)NR * NC;

    k_init<<<(NR * NC + 255) / 256, 256, 0, stream>>>(bbuf, cbuf);
    {
        dim3 gt(NR / 128, NB / 8);
        k_transpose<<<gt, 256, 0, stream>>>(x, xT);
    }

    dim3 ghot(nchunk, NC);        // linear id = ch + nchunk*c; nchunk%8==0 ->
                                  // blocks sharing an x-slice land on one XCD
    dim3 gr1(40, E);

    for (int it = 0; it < 3; ++it) {
        if (nchunk == 128)
            k_partial<128, 9><<<ghot, 256, 0, stream>>>(xT, W, cbuf, part);
        else if (nchunk == 64)
            k_partial<64, 18><<<ghot, 256, 0, stream>>>(xT, W, cbuf, part);
        else
            k_partial<32, 36><<<ghot, 256, 0, stream>>>(xT, W, cbuf, part);

        k_reduce1<<<gr1, 256, 0, stream>>>(part, part2, nchunk, E);
        k_reduce2<<<40, 256, 0, stream>>>(part2, vbuf, out, E, it == 2 ? 1 : 0);

        if (it < 2) {
            if (nchunk == 128)
                k_agree<128, 9><<<ghot, 256, 0, stream>>>(xT, W, vbuf, bbuf);
            else if (nchunk == 64)
                k_agree<64, 18><<<ghot, 256, 0, stream>>>(xT, W, vbuf, bbuf);
            else
                k_agree<32, 36><<<ghot, 256, 0, stream>>>(xT, W, vbuf, bbuf);
            k_softmax<<<NC, 256, 0, stream>>>(bbuf, cbuf);
        }
    }
}